// Round 17
// baseline (79.283 us; speedup 1.0000x reference)
//
#include <hip/hip_runtime.h>
#include <hip/hip_fp8.h>

#define D 256
#define SCALE 1.69864354f   // sqrt((1/T)*log2e), T=0.5: acc=2.8854*cos -> exp2(acc)=exp(sim/T)
#define EPS 1e-8f

typedef __attribute__((ext_vector_type(4))) float f32x4;
typedef long fp8x8;   // 8 packed e4m3 bytes = one MFMA A/B fragment register pair

// ------ Kernel A: row-normalize [z1;z2] -> fp8 fn (pre-scaled), fused pos ---
// Also zeroes denomacc (blocks 0..31) and the finale sync counter (block 0):
// runs before denom in stream order, re-zeroing every call (no replay state).
__global__ __launch_bounds__(256) void normpos_kernel(
    const float* __restrict__ z1, const float* __restrict__ z2,
    unsigned char* __restrict__ fnq, float* __restrict__ pos,
    float* __restrict__ denomacc, int* __restrict__ sync, int N) {
  if (blockIdx.x == 0 && threadIdx.x == 0) *sync = 0;
  if (blockIdx.x < 32) denomacc[blockIdx.x * 256 + threadIdx.x] = 0.f;
  int wid  = threadIdx.x >> 6;
  int lane = threadIdx.x & 63;
  int row  = blockIdx.x * 4 + wid;
  f32x4 a = *(const f32x4*)(z1 + (size_t)row * D + lane * 4);
  f32x4 b = *(const f32x4*)(z2 + (size_t)row * D + lane * 4);
  float s1  = a.x * a.x + a.y * a.y + a.z * a.z + a.w * a.w;
  float s2  = b.x * b.x + b.y * b.y + b.z * b.z + b.w * b.w;
  float dot = a.x * b.x + a.y * b.y + a.z * b.z + a.w * b.w;
  #pragma unroll
  for (int m = 1; m < 64; m <<= 1) {
    s1  += __shfl_xor(s1, m, 64);
    s2  += __shfl_xor(s2, m, 64);
    dot += __shfl_xor(dot, m, 64);
  }
  float inv1 = 1.0f / fmaxf(sqrtf(s1), EPS);
  float inv2 = 1.0f / fmaxf(sqrtf(s2), EPS);
  float q1 = inv1 * SCALE, q2 = inv2 * SCALE;
  unsigned int w1 = 0, w2 = 0;
  #pragma unroll
  for (int j = 0; j < 4; ++j) {
    w1 |= (unsigned int)__hip_cvt_float_to_fp8(a[j] * q1, __HIP_SATFINITE,
                                               __HIP_E4M3) << (8 * j);
    w2 |= (unsigned int)__hip_cvt_float_to_fp8(b[j] * q2, __HIP_SATFINITE,
                                               __HIP_E4M3) << (8 * j);
  }
  *(unsigned int*)(fnq + (size_t)row * D + lane * 4)       = w1;
  *(unsigned int*)(fnq + (size_t)(N + row) * D + lane * 4) = w2;
  if (lane == 0) pos[row] = dot * inv1 * inv2;
}

// -------- Kernel B: denom + full reduction, fp8 upper-triangle GEMM --------
// R13 proven skeleton (52.8us): 128x128 tile, 4 waves, single-buffered,
// BK=128 (2 kk x 4 ks, 64 MFMA per barrier-pair), launch_bounds(256,4),
// LDS 34 KB -> 4 blocks/CU. New in R17: row/col sums atomicAdd directly
// into denomacc[8192] (no partial buffer, no reduce kernel); last block
// (atomic counter) computes loss = mean(log denomacc) - 2*mean(pos).
// Triangle rb<=cb. Chunk swizzle: inverse-swizzled GLOBAL source +
// swizzled ds_read, linear LDS dest (rule #21).
// mfma_f32_16x16x32_fp8_fp8: A/B row/col=lane&15, k-byte=(lane>>4)*8+j;
// C/D col=lane&15, row=(lane>>4)*4+reg (dtype-independent, m121-m128).

__device__ __forceinline__ void stage_tile(const unsigned char* __restrict__ row0,
                                           int kk, unsigned char* lds, int tid) {
  // 128 rows x 128 k fp8 (16 KB) = 1024 chunks of 16B; 4 iters x 256 thr.
  #pragma unroll
  for (int it = 0; it < 4; ++it) {
    int s = it * 256 + tid;        // chunk slot; per-wave base + lane*16B ✓
    int r = s >> 3;                // row in tile
    int p = s & 7;                 // chunk-in-row (LDS position)
    const unsigned char* src =
        row0 + (size_t)r * D + kk * 128 + ((p ^ (r & 7)) << 4);
    __builtin_amdgcn_global_load_lds(
        (const __attribute__((address_space(1))) void*)src,
        (__attribute__((address_space(3))) void*)(lds + s * 16), 16, 0, 0);
  }
}

__global__ __launch_bounds__(256, 4) void denom_kernel(
    const unsigned char* __restrict__ fnq, float* __restrict__ denomacc,
    const float* __restrict__ pos, float* __restrict__ out,
    int* __restrict__ sync, int twoN, int N, int ntri) {
  __shared__ unsigned char As[128 * 128];   // 16 KB
  __shared__ unsigned char Bs[128 * 128];   // 16 KB
  __shared__ float redR[128][2];            // 2 KB
  __shared__ float redC[128][2];

  int tid  = threadIdx.x;
  int wid  = tid >> 6;
  int lane = tid & 63;
  int c = lane & 15;            // frag row/col within 16-tile
  int g = lane >> 4;            // k-group (in) / row-group (out)
  int wr = wid >> 1, wc = wid & 1;

  // decode lower-triangle linear index -> (rb<=cb)
  int bid = blockIdx.x;
  int i = (int)((sqrtf(8.f * (float)bid + 1.f) - 1.f) * 0.5f);
  while ((i + 1) * (i + 2) / 2 <= bid) ++i;
  while (i * (i + 1) / 2 > bid) --i;
  int rb = bid - i * (i + 1) / 2;   // row block  (rb <= cb)
  int cb = i;                       // col block
  const unsigned char* Arow0 = fnq + (size_t)rb * 128 * D;
  const unsigned char* Brow0 = fnq + (size_t)cb * 128 * D;

  bool dblk  = (rb == cb);
  bool dwave = dblk && (wr == wc);

  f32x4 acc[4][4] = {};

  stage_tile(Arow0, 0, As, tid);
  stage_tile(Brow0, 0, Bs, tid);

  #pragma unroll
  for (int kk = 0; kk < 2; ++kk) {
    __syncthreads();   // stage complete (vmcnt drained before barrier)
    #pragma unroll
    for (int ks = 0; ks < 4; ++ks) {
      fp8x8 a[4], b[4];
      int q  = (ks << 1) | (g >> 1);   // 16B-chunk index of this k-group
      int h  = (g & 1) << 3;           // 8B half within chunk
      #pragma unroll
      for (int mi = 0; mi < 4; ++mi) {
        int ar = wr * 64 + mi * 16 + c;
        a[mi] = *(const fp8x8*)(As + ar * 128 + ((q ^ (ar & 7)) << 4) + h);
      }
      #pragma unroll
      for (int ni = 0; ni < 4; ++ni) {
        int bc = wc * 64 + ni * 16 + c;
        b[ni] = *(const fp8x8*)(Bs + bc * 128 + ((q ^ (bc & 7)) << 4) + h);
      }
      #pragma unroll
      for (int mi = 0; mi < 4; ++mi)
        #pragma unroll
        for (int ni = 0; ni < 4; ++ni)
          acc[mi][ni] = __builtin_amdgcn_mfma_f32_16x16x32_fp8_fp8(
              a[mi], b[ni], acc[mi][ni], 0, 0, 0);
    }
    if (kk == 0) {
      __syncthreads();               // protect LDS before restage
      stage_tile(Arow0, 1, As, tid);
      stage_tile(Brow0, 1, Bs, tid);
    }
  }

  // ---- epilogue: e = exp2(acc) (scale pre-folded); 3 wave-uniform paths ----
  float rsum[16];
  float csum[4];
  #pragma unroll
  for (int ii = 0; ii < 16; ++ii) rsum[ii] = 0.f;
  #pragma unroll
  for (int ii = 0; ii < 4; ++ii) csum[ii] = 0.f;

  if (dwave) {
    #pragma unroll
    for (int mi = 0; mi < 4; ++mi)
      #pragma unroll
      for (int ni = 0; ni < 4; ++ni) {
        int colloc = ni * 16 + c;
        #pragma unroll
        for (int r = 0; r < 4; ++r) {
          int rowloc = mi * 16 + g * 4 + r;
          float e = __builtin_amdgcn_exp2f(acc[mi][ni][r]);
          if (rowloc == colloc) e = 0.f;
          rsum[mi * 4 + r] += e;
        }
      }
  } else if (dblk) {
    #pragma unroll
    for (int mi = 0; mi < 4; ++mi)
      #pragma unroll
      for (int ni = 0; ni < 4; ++ni)
        #pragma unroll
        for (int r = 0; r < 4; ++r)
          rsum[mi * 4 + r] += __builtin_amdgcn_exp2f(acc[mi][ni][r]);
  } else {
    #pragma unroll
    for (int mi = 0; mi < 4; ++mi)
      #pragma unroll
      for (int ni = 0; ni < 4; ++ni)
        #pragma unroll
        for (int r = 0; r < 4; ++r) {
          float e = __builtin_amdgcn_exp2f(acc[mi][ni][r]);
          rsum[mi * 4 + r] += e;
          csum[ni]         += e;
        }
  }

  // row sums: reduce across the 16 column-lanes (lane bits 0-3)
  #pragma unroll
  for (int ii = 0; ii < 16; ++ii) {
    float v = rsum[ii];
    v += __shfl_xor(v, 1, 64);
    v += __shfl_xor(v, 2, 64);
    v += __shfl_xor(v, 4, 64);
    v += __shfl_xor(v, 8, 64);
    rsum[ii] = v;
  }
  if (c == 0) {
    #pragma unroll
    for (int mi = 0; mi < 4; ++mi)
      #pragma unroll
      for (int r = 0; r < 4; ++r)
        redR[wr * 64 + mi * 16 + g * 4 + r][wc] = rsum[mi * 4 + r];
  }
  if (!dblk) {
    // col sums: reduce across the 4 row-groups g (lane bits 4-5)
    #pragma unroll
    for (int ii = 0; ii < 4; ++ii) {
      float v = csum[ii];
      v += __shfl_xor(v, 16, 64);
      v += __shfl_xor(v, 32, 64);
      csum[ii] = v;
    }
    if (g == 0) {
      #pragma unroll
      for (int ni = 0; ni < 4; ++ni)
        redC[wc * 64 + ni * 16 + c][wr] = csum[ni];
    }
  }
  __syncthreads();
  // ---- direct atomic accumulation into denomacc (no partial buffer) ----
  if (tid < 128) {
    atomicAdd(denomacc + rb * 128 + tid, redR[tid][0] + redR[tid][1]);
    if (rb != cb)
      atomicAdd(denomacc + cb * 128 + tid, redC[tid][0] + redC[tid][1]);
  }
  __syncthreads();   // drains vmcnt: all this block's atomics issued+complete

  // ---- last-block finale: loss = mean(log denom) - 2*mean(pos) ----
  __shared__ int lastf;
  if (tid == 0) {
    __threadfence();
    lastf = (atomicAdd(sync, 1) == ntri - 1);
  }
  __syncthreads();
  if (lastf) {
    __threadfence();   // acquire all other blocks' atomics
    float ls = 0.f, ps = 0.f;
    for (int r = tid; r < twoN; r += 256) ls += logf(denomacc[r]);
    for (int r = tid; r < N; r += 256) ps += pos[r];
    #pragma unroll
    for (int m = 1; m < 64; m <<= 1) {
      ls += __shfl_xor(ls, m, 64);
      ps += __shfl_xor(ps, m, 64);
    }
    __shared__ float sl[4], sp[4];
    if (lane == 0) { sl[wid] = ls; sp[wid] = ps; }
    __syncthreads();
    if (tid == 0)
      out[0] = (sl[0] + sl[1] + sl[2] + sl[3]) / (float)twoN -
               2.f * (sp[0] + sp[1] + sp[2] + sp[3]) / (float)N;
  }
}

extern "C" void kernel_launch(void* const* d_in, const int* in_sizes, int n_in,
                              void* d_out, int out_size, void* d_ws,
                              size_t ws_size, hipStream_t stream) {
  const float* z1 = (const float*)d_in[0];
  const float* z2 = (const float*)d_in[1];
  int N = in_sizes[0] / D;   // 4096
  int twoN = 2 * N;          // 8192

  // workspace layout
  unsigned char* fnq = (unsigned char*)d_ws;                       // 2 MB fp8
  float* denomacc = (float*)((char*)d_ws + (size_t)twoN * D);      // 32 KB
  float* pos      = (float*)((char*)denomacc + (size_t)twoN * 4);  // 16 KB
  int*   sync     = (int*)((char*)pos + (size_t)N * 4);

  normpos_kernel<<<N / 4, 256, 0, stream>>>(z1, z2, fnq, pos, denomacc, sync, N);
  int nrb = twoN / 128;            // 64
  int ntri = nrb * (nrb + 1) / 2;  // 2080 upper-triangle blocks
  denom_kernel<<<ntri, 256, 0, stream>>>(fnq, denomacc, pos, (float*)d_out,
                                         sync, twoN, N, ntri);
}

// Round 18
// 69.607 us; speedup vs baseline: 1.1390x; 1.1390x over previous
//
#include <hip/hip_runtime.h>
#include <hip/hip_fp8.h>

#define D 256
#define SCALE 1.69864354f   // sqrt((1/T)*log2e), T=0.5: acc=2.8854*cos -> exp2(acc)=exp(sim/T)
#define EPS 1e-8f

typedef __attribute__((ext_vector_type(4))) float f32x4;
typedef long fp8x8;   // 8 packed e4m3 bytes = one MFMA A/B fragment register pair

// ------ Kernel A: row-normalize [z1;z2] -> fp8 fn (pre-scaled), fused pos ---
// Also zeroes the reduce sync counter (runs before reduce in stream order).
__global__ __launch_bounds__(256) void normpos_kernel(
    const float* __restrict__ z1, const float* __restrict__ z2,
    unsigned char* __restrict__ fnq, float* __restrict__ pos,
    int* __restrict__ sync, int N) {
  if (blockIdx.x == 0 && threadIdx.x == 0) *sync = 0;
  int wid  = threadIdx.x >> 6;
  int lane = threadIdx.x & 63;
  int row  = blockIdx.x * 4 + wid;
  f32x4 a = *(const f32x4*)(z1 + (size_t)row * D + lane * 4);
  f32x4 b = *(const f32x4*)(z2 + (size_t)row * D + lane * 4);
  float s1  = a.x * a.x + a.y * a.y + a.z * a.z + a.w * a.w;
  float s2  = b.x * b.x + b.y * b.y + b.z * b.z + b.w * b.w;
  float dot = a.x * b.x + a.y * b.y + a.z * b.z + a.w * b.w;
  #pragma unroll
  for (int m = 1; m < 64; m <<= 1) {
    s1  += __shfl_xor(s1, m, 64);
    s2  += __shfl_xor(s2, m, 64);
    dot += __shfl_xor(dot, m, 64);
  }
  float inv1 = 1.0f / fmaxf(sqrtf(s1), EPS);
  float inv2 = 1.0f / fmaxf(sqrtf(s2), EPS);
  float q1 = inv1 * SCALE, q2 = inv2 * SCALE;
  unsigned int w1 = 0, w2 = 0;
  #pragma unroll
  for (int j = 0; j < 4; ++j) {
    w1 |= (unsigned int)__hip_cvt_float_to_fp8(a[j] * q1, __HIP_SATFINITE,
                                               __HIP_E4M3) << (8 * j);
    w2 |= (unsigned int)__hip_cvt_float_to_fp8(b[j] * q2, __HIP_SATFINITE,
                                               __HIP_E4M3) << (8 * j);
  }
  *(unsigned int*)(fnq + (size_t)row * D + lane * 4)       = w1;
  *(unsigned int*)(fnq + (size_t)(N + row) * D + lane * 4) = w2;
  if (lane == 0) pos[row] = dot * inv1 * inv2;
}

// -------- Kernel B: denom partials, fp8 pipelined upper-triangle GEMM ------
// New schedule vs R13 (kept: 128x128 tile, 4 waves, fp8, triangle, partial
// writes, launch_bounds(256,4)):
//  (1) BK=64 DOUBLE-buffer (4x8KB+2KB = 34KB, still 4 blocks/CU): stage(u+1)
//      issued BEFORE compute(u); one barrier/step whose vmcnt drain is cheap
//      (loads fly under 32 MFMAs). Buffer parity: writers of buf[(u+1)&1]
//      passed barrier(u-1) whose readers finished compute(u-1) -> race-free.
//  (2) BK=64 row stride 64B restores bank bit4 (ar*16 mod 32 alternates):
//      fewer ds_read_b64 conflicts than BK=128 (R17 measured 2.1M).
//  (3) TWO consecutive triangle tiles per block (grid 1040 ~ 1.02
//      generations of 1024 resident, was 2.03): tail removed, prologue
//      amortized, tile0 epilogue overlaps tile1 stage/compute.
// Chunk swizzle: inverse-swizzled GLOBAL source + swizzled ds_read, linear
// LDS dest (rule #21): LDS slot p holds global chunk p^(r&3); read addr
// (q^(ar&3))<<4. mfma_f32_16x16x32_fp8_fp8: A/B row/col=lane&15,
// k-byte=(lane>>4)*8+j; C/D col=lane&15, row=(lane>>4)*4+reg (m121-m128).

__device__ __forceinline__ void stage64(const unsigned char* __restrict__ row0,
                                        int kk, unsigned char* lds, int tid) {
  // 128 rows x 64B (8KB) = 512 chunks of 16B; 2 iters x 256 threads.
  #pragma unroll
  for (int it = 0; it < 2; ++it) {
    int s = it * 256 + tid;
    int r = s >> 2;                // row (4 chunks per 64B row)
    int p = s & 3;                 // chunk-in-row (LDS position)
    const unsigned char* src =
        row0 + (size_t)r * D + kk * 64 + ((p ^ (r & 3)) << 4);
    __builtin_amdgcn_global_load_lds(
        (const __attribute__((address_space(1))) void*)src,
        (__attribute__((address_space(3))) void*)(lds + s * 16), 16, 0, 0);
  }
}

__global__ __launch_bounds__(256, 4) void denom_kernel(
    const unsigned char* __restrict__ fnq, float* __restrict__ partial,
    int twoN) {
  __shared__ unsigned char As[2][128 * 64];   // 2 x 8 KB
  __shared__ unsigned char Bs[2][128 * 64];   // 2 x 8 KB
  __shared__ float redR[128][2];              // 1 KB
  __shared__ float redC[128][2];              // 1 KB

  int tid  = threadIdx.x;
  int wid  = tid >> 6;
  int lane = tid & 63;
  int c = lane & 15;            // frag row/col within 16-tile
  int g = lane >> 4;            // k-group (in) / row-group (out)
  int wr = wid >> 1, wc = wid & 1;

  // decode the block's TWO consecutive lower-triangle tiles (rb<=cb)
  int rbs[2], cbs[2];
  #pragma unroll
  for (int j = 0; j < 2; ++j) {
    int bid = 2 * blockIdx.x + j;
    int i = (int)((sqrtf(8.f * (float)bid + 1.f) - 1.f) * 0.5f);
    while ((i + 1) * (i + 2) / 2 <= bid) ++i;
    while (i * (i + 1) / 2 > bid) --i;
    rbs[j] = bid - i * (i + 1) / 2;
    cbs[j] = i;
  }
  const unsigned char* Ar[2] = {fnq + (size_t)rbs[0] * 128 * D,
                                fnq + (size_t)rbs[1] * 128 * D};
  const unsigned char* Br[2] = {fnq + (size_t)cbs[0] * 128 * D,
                                fnq + (size_t)cbs[1] * 128 * D};

  stage64(Ar[0], 0, As[0], tid);
  stage64(Br[0], 0, Bs[0], tid);
  __syncthreads();   // prologue drain

  f32x4 acc[4][4] = {};
  #pragma unroll
  for (int u = 0; u < 8; ++u) {       // u = tile*4 + kk
    const int j  = u >> 2;
    const int kk = u & 3;
    const int cur = u & 1;
    if (u < 7) {                      // issue next stage BEFORE compute
      stage64(Ar[(u + 1) >> 2], (u + 1) & 3, As[cur ^ 1], tid);
      stage64(Br[(u + 1) >> 2], (u + 1) & 3, Bs[cur ^ 1], tid);
    }
    // ---- compute K-slice kk of tile j from buffer cur ----
    #pragma unroll
    for (int ks = 0; ks < 2; ++ks) {
      fp8x8 a[4], b[4];
      int q = (ks << 1) | (g >> 1);   // 16B chunk of this k-group
      int h = (g & 1) << 3;           // 8B half within chunk
      #pragma unroll
      for (int mi = 0; mi < 4; ++mi) {
        int ar = wr * 64 + mi * 16 + c;
        a[mi] = *(const fp8x8*)(As[cur] + ar * 64 + ((q ^ (ar & 3)) << 4) + h);
      }
      #pragma unroll
      for (int ni = 0; ni < 4; ++ni) {
        int bc = wc * 64 + ni * 16 + c;
        b[ni] = *(const fp8x8*)(Bs[cur] + bc * 64 + ((q ^ (bc & 3)) << 4) + h);
      }
      #pragma unroll
      for (int mi = 0; mi < 4; ++mi)
        #pragma unroll
        for (int ni = 0; ni < 4; ++ni)
          acc[mi][ni] = __builtin_amdgcn_mfma_f32_16x16x32_fp8_fp8(
              a[mi], b[ni], acc[mi][ni], 0, 0, 0);
    }
    if (kk == 3) {
      // ---- epilogue for tile j: exp2, rowsum (+colsum), red writes ----
      bool dblk  = (rbs[j] == cbs[j]);
      bool dwave = dblk && (wr == wc);
      float rsum[16];
      float csum[4];
      #pragma unroll
      for (int ii = 0; ii < 16; ++ii) rsum[ii] = 0.f;
      #pragma unroll
      for (int ii = 0; ii < 4; ++ii) csum[ii] = 0.f;
      if (dwave) {
        #pragma unroll
        for (int mi = 0; mi < 4; ++mi)
          #pragma unroll
          for (int ni = 0; ni < 4; ++ni) {
            int colloc = ni * 16 + c;
            #pragma unroll
            for (int r = 0; r < 4; ++r) {
              int rowloc = mi * 16 + g * 4 + r;
              float e = __builtin_amdgcn_exp2f(acc[mi][ni][r]);
              if (rowloc == colloc) e = 0.f;
              rsum[mi * 4 + r] += e;
            }
          }
      } else if (dblk) {
        #pragma unroll
        for (int mi = 0; mi < 4; ++mi)
          #pragma unroll
          for (int ni = 0; ni < 4; ++ni)
            #pragma unroll
            for (int r = 0; r < 4; ++r)
              rsum[mi * 4 + r] += __builtin_amdgcn_exp2f(acc[mi][ni][r]);
      } else {
        #pragma unroll
        for (int mi = 0; mi < 4; ++mi)
          #pragma unroll
          for (int ni = 0; ni < 4; ++ni)
            #pragma unroll
            for (int r = 0; r < 4; ++r) {
              float e = __builtin_amdgcn_exp2f(acc[mi][ni][r]);
              rsum[mi * 4 + r] += e;
              csum[ni]         += e;
            }
      }
      #pragma unroll
      for (int ii = 0; ii < 16; ++ii) {
        float v = rsum[ii];
        v += __shfl_xor(v, 1, 64);
        v += __shfl_xor(v, 2, 64);
        v += __shfl_xor(v, 4, 64);
        v += __shfl_xor(v, 8, 64);
        rsum[ii] = v;
      }
      if (c == 0) {
        #pragma unroll
        for (int mi = 0; mi < 4; ++mi)
          #pragma unroll
          for (int r = 0; r < 4; ++r)
            redR[wr * 64 + mi * 16 + g * 4 + r][wc] = rsum[mi * 4 + r];
      }
      if (!dblk) {
        #pragma unroll
        for (int ii = 0; ii < 4; ++ii) {
          float v = csum[ii];
          v += __shfl_xor(v, 16, 64);
          v += __shfl_xor(v, 32, 64);
          csum[ii] = v;
        }
        if (g == 0) {
          #pragma unroll
          for (int ni = 0; ni < 4; ++ni)
            redC[wc * 64 + ni * 16 + c][wr] = csum[ni];
        }
      }
      // reset accumulator for the next tile
      #pragma unroll
      for (int mi = 0; mi < 4; ++mi)
        #pragma unroll
        for (int ni = 0; ni < 4; ++ni)
          acc[mi][ni] = f32x4{0.f, 0.f, 0.f, 0.f};
    }
    __syncthreads();   // step barrier: drains stage(u+1); red ready if kk==3
    if (kk == 3 && tid < 128) {
      // partial writes for tile j (global stores overlap next compute)
      partial[(size_t)cbs[j] * twoN + rbs[j] * 128 + tid] =
          redR[tid][0] + redR[tid][1];
      if (rbs[j] != cbs[j])
        partial[(size_t)rbs[j] * twoN + cbs[j] * 128 + tid] =
            redC[tid][0] + redC[tid][1];
    }
  }
}

// ---- Kernel C: per-256-row sums of log(denom), pos; last block finishes ----
__global__ __launch_bounds__(256) void reduce_kernel(
    const float* __restrict__ partial, const float* __restrict__ pos,
    float* __restrict__ bsum, float* __restrict__ out, int* __restrict__ sync,
    int twoN, int N, int nsplit) {
  int row = blockIdx.x * 256 + threadIdx.x;
  int wid = threadIdx.x >> 6, lane = threadIdx.x & 63;
  float denom = 0.f;
  for (int s = 0; s < nsplit; ++s) denom += partial[(size_t)s * twoN + row];
  float ld = logf(denom);
  float p  = (row < N) ? pos[row] : 0.f;
  #pragma unroll
  for (int m = 1; m < 64; m <<= 1) {
    ld += __shfl_xor(ld, m, 64);
    p  += __shfl_xor(p, m, 64);
  }
  __shared__ float sld[4], spo[4];
  __shared__ int lastf;
  if (lane == 0) { sld[wid] = ld; spo[wid] = p; }
  __syncthreads();
  if (threadIdx.x == 0) {
    bsum[blockIdx.x]             = sld[0] + sld[1] + sld[2] + sld[3];
    bsum[gridDim.x + blockIdx.x] = spo[0] + spo[1] + spo[2] + spo[3];
    __threadfence();
    lastf = (atomicAdd(sync, 1) == (int)gridDim.x - 1);
  }
  __syncthreads();
  if (lastf && threadIdx.x < 64) {
    __threadfence();   // acquire other blocks' bsum
    int t = threadIdx.x;
    int nb = gridDim.x;
    float l2 = (t < nb) ? bsum[t] : 0.f;
    float p2 = (t < nb) ? bsum[nb + t] : 0.f;
    #pragma unroll
    for (int m = 1; m < 64; m <<= 1) {
      l2 += __shfl_xor(l2, m, 64);
      p2 += __shfl_xor(p2, m, 64);
    }
    if (t == 0) out[0] = l2 / (float)twoN - 2.f * (p2 / (float)N);
  }
}

extern "C" void kernel_launch(void* const* d_in, const int* in_sizes, int n_in,
                              void* d_out, int out_size, void* d_ws,
                              size_t ws_size, hipStream_t stream) {
  const float* z1 = (const float*)d_in[0];
  const float* z2 = (const float*)d_in[1];
  int N = in_sizes[0] / D;   // 4096
  int twoN = 2 * N;          // 8192
  int nrb = twoN / 128;      // 64 (= nsplit)

  // workspace layout
  unsigned char* fnq = (unsigned char*)d_ws;                     // 2 MB fp8
  float* partial = (float*)((char*)d_ws + (size_t)twoN * D);     // 2 MB
  float* pos     = (float*)((char*)partial + (size_t)nrb * twoN * 4);
  float* bsum    = (float*)((char*)pos + (size_t)N * 4);         // 64 floats
  int*   sync    = (int*)((char*)bsum + 256 * 4);

  normpos_kernel<<<N / 4, 256, 0, stream>>>(z1, z2, fnq, pos, sync, N);
  int ntri = nrb * (nrb + 1) / 2;  // 2080 tiles -> 1040 blocks x 2 tiles
  denom_kernel<<<ntri / 2, 256, 0, stream>>>(fnq, partial, twoN);
  int nblk = twoN / 256;  // 32
  reduce_kernel<<<nblk, 256, 0, stream>>>(partial, pos, bsum, (float*)d_out,
                                          sync, twoN, N, nrb);
}